// Round 2
// baseline (23017.683 us; speedup 1.0000x reference)
//
#include <hip/hip_runtime.h>

#define NN   2048
#define TT   2048
#define LSIG 128
#define MOMC 0.999f
#define EPSC 1e-32f
#define NBLK 256
#define NTHR 512   // 8 waves

// ws layout (bytes):
//   flags : int[256]        @ 0
//   colsum: float[2048]     @ 1024
//   bufs  : float[2][2048]  @ 9216   (Snext double buffer by step parity)
#define WS_WORDS ((1024 + 8192 + 16384) / 4)

__global__ void sp_init(float* ws_f) {
  int i = blockIdx.x * blockDim.x + threadIdx.x;
  int stride = gridDim.x * blockDim.x;
  for (; i < WS_WORDS; i += stride) ws_f[i] = 0.0f;
}

__global__ void sp_colsum(const float* __restrict__ A, float* __restrict__ colsum) {
  int b = blockIdx.x;
  for (int c = threadIdx.x; c < NN; c += blockDim.x) {
    float s = 0.f;
#pragma unroll
    for (int r = 0; r < 8; ++r) s += A[(size_t)(b * 8 + r) * NN + c];
    atomicAdd(&colsum[c], s);
  }
}

__global__ __launch_bounds__(NTHR) void sp_persist(
    const float* __restrict__ A, const float* __restrict__ sig,
    float* __restrict__ out, const float* __restrict__ colsum,
    float* __restrict__ bufs, int* __restrict__ flags) {

  __shared__ float P_lds[NN];      // running P vector (full)
  __shared__ float S_lds[NN];      // current S vector (full)
  __shared__ float sig_lds[LSIG];
  __shared__ float red_lds[8][2];  // per-wave partial row sums
  __shared__ float rw_lds[8];      // rowsum(W) for our 8 rows = colsum/(colsum+eps)

  const int tid  = threadIdx.x;
  const int b    = blockIdx.x;
  const int w    = tid >> 6;       // wave 0..7
  const int lane = tid & 63;
  const int p    = w >> 1;         // row-pair 0..3
  const int h    = w & 1;          // which half of i-range
  const int row0 = b * 8 + p * 2;  // this wave's rows: row0, row0+1
  const int i0   = h * 1024 + lane * 16;

  if (tid < LSIG) sig_lds[tid] = sig[tid];

  // ---- load our 2 W^T-columns into registers:
  //      wt[k] = A[row][i0+k] / (colsum[i0+k]+eps)  ( = W[i][row] )
  float wt0[16], wt1[16];
  {
    const float* a0 = A + (size_t)row0 * NN + i0;
    const float* a1 = a0 + NN;
    const float* cs = colsum + i0;
#pragma unroll
    for (int k = 0; k < 16; ++k) {
      float c = cs[k] + EPSC;
      wt0[k] = a0[k] / c;
      wt1[k] = a1[k] / c;
    }
  }
  // zero P
#pragma unroll
  for (int k = 0; k < 4; ++k) P_lds[tid * 4 + k] = 0.f;

  // ---- rowsum(W)[j] = colsum[j] / (colsum[j]+eps)   (== 1.0f in fp32)
  if (tid < 8) {
    float c = colsum[b * 8 + tid];
    rw_lds[tid] = c / (c + EPSC);
  }
  __syncthreads();

  for (int t = 0; t < TT; ++t) {
    // ---- wait for all blocks to have published Snext_{t-1}
    if (t > 0) {
      if (w == 0) {
        int* fl = flags + lane * 4;
        for (;;) {
          int a0 = __hip_atomic_load(fl + 0, __ATOMIC_RELAXED, __HIP_MEMORY_SCOPE_AGENT);
          int a1 = __hip_atomic_load(fl + 1, __ATOMIC_RELAXED, __HIP_MEMORY_SCOPE_AGENT);
          int a2 = __hip_atomic_load(fl + 2, __ATOMIC_RELAXED, __HIP_MEMORY_SCOPE_AGENT);
          int a3 = __hip_atomic_load(fl + 3, __ATOMIC_RELAXED, __HIP_MEMORY_SCOPE_AGENT);
          if (__all(a0 >= t && a1 >= t && a2 >= t && a3 >= t)) break;
          __builtin_amdgcn_s_sleep(1);
        }
      }
      __syncthreads();
    }

    // ---- S = Snext_prev + s_t ; P = S + mom*P ; write out for own rows
    const float s_t = sig_lds[t % (LSIG - 1)];
    float* bprev = bufs + (t & 1) * NN;
    {
      int ib = tid * 4;
      float Sl[4];
#pragma unroll
      for (int k = 0; k < 4; ++k) {
        float sv = __hip_atomic_load(bprev + ib + k, __ATOMIC_RELAXED, __HIP_MEMORY_SCOPE_AGENT);
        float S  = sv + s_t;
        float pn = fmaf(MOMC, P_lds[ib + k], S);
        P_lds[ib + k] = pn;
        S_lds[ib + k] = S;
        Sl[k] = S;
      }
      if ((tid >> 1) == b) {          // this thread's i-range is our own 8 rows
#pragma unroll
        for (int k = 0; k < 4; ++k) out[(size_t)(ib + k) * TT + t] = Sl[k];
      }
    }
    __syncthreads();

    // ---- y[j] = (W^T P)[j] = sum_i A[j][i]/(colsum[i]+eps) * P[i], our rows
    {
      const float4* pv = (const float4*)(P_lds + i0);
      float4 q0 = pv[0], q1 = pv[1], q2 = pv[2], q3 = pv[3];
      float pp_[16] = {q0.x, q0.y, q0.z, q0.w, q1.x, q1.y, q1.z, q1.w,
                       q2.x, q2.y, q2.z, q2.w, q3.x, q3.y, q3.z, q3.w};
      float y0 = 0.f, y1 = 0.f;
#pragma unroll
      for (int k = 0; k < 16; ++k) {
        y0 = fmaf(wt0[k], pp_[k], y0);
        y1 = fmaf(wt1[k], pp_[k], y1);
      }
#pragma unroll
      for (int m = 1; m < 64; m <<= 1) { y0 += __shfl_xor(y0, m); y1 += __shfl_xor(y1, m); }
      if (lane == 0) { red_lds[w][0] = y0; red_lds[w][1] = y1; }
    }
    __syncthreads();

    // ---- Snext[j] = S[j] + y[j] - P[j]*rW[j]; publish + flag
    if (tid < 8) {
      int j  = b * 8 + tid;
      int pp = tid >> 1, rr = tid & 1;
      float y  = red_lds[pp * 2][rr] + red_lds[pp * 2 + 1][rr];
      float sn = (S_lds[j] + y) - P_lds[j] * rw_lds[tid];
      float* bn = bufs + ((t + 1) & 1) * NN;
      __hip_atomic_store(bn + j, sn, __ATOMIC_RELAXED, __HIP_MEMORY_SCOPE_AGENT);
      __threadfence();                // drain our stores to the coherence point
    }
    __syncthreads();
    if (tid == 0)
      __hip_atomic_store(flags + b, t + 1, __ATOMIC_RELEASE, __HIP_MEMORY_SCOPE_AGENT);
  }
}

extern "C" void kernel_launch(void* const* d_in, const int* in_sizes, int n_in,
                              void* d_out, int out_size, void* d_ws, size_t ws_size,
                              hipStream_t stream) {
  const float* A   = (const float*)d_in[0];
  const float* sig = (const float*)d_in[1];
  float* out = (float*)d_out;
  char*  ws  = (char*)d_ws;

  int*   flags  = (int*)ws;
  float* colsum = (float*)(ws + 1024);
  float* bufs   = (float*)(ws + 1024 + 8192);

  sp_init<<<32, 256, 0, stream>>>((float*)ws);
  sp_colsum<<<NBLK, 256, 0, stream>>>(A, colsum);
  sp_persist<<<NBLK, NTHR, 0, stream>>>(A, sig, out, colsum, bufs, flags);
}

// Round 3
// 11250.835 us; speedup vs baseline: 2.0459x; 2.0459x over previous
//
#include <hip/hip_runtime.h>

#define NN   2048
#define TT   2048
#define LSIG 128
#define MOMC 0.999f
#define EPSC 1e-32f
#define NBLK 256
#define NTHR 512   // 8 waves

// ws layout: pub ull[2][2048] @ 0 (32 KB); colsum float[2048] @ 32768 (8 KB)
// pub word: (tag<<32) | float_bits ; tag t = "value consumed at step t", parity t&1
#define WS_WORDS ((32768 + 8192) / 4)

__global__ void sp_init(unsigned int* ws) {
  int i = blockIdx.x * blockDim.x + threadIdx.x;
  int stride = gridDim.x * blockDim.x;
  for (; i < WS_WORDS; i += stride) ws[i] = 0u;
}

__global__ void sp_colsum(const float* __restrict__ A, float* __restrict__ colsum) {
  int b = blockIdx.x;
  for (int c = threadIdx.x; c < NN; c += blockDim.x) {
    float s = 0.f;
#pragma unroll
    for (int r = 0; r < 8; ++r) s += A[(size_t)(b * 8 + r) * NN + c];
    atomicAdd(&colsum[c], s);
  }
}

__global__ __launch_bounds__(NTHR) void sp_persist(
    const float* __restrict__ A, const float* __restrict__ sig,
    float* __restrict__ out, const float* __restrict__ colsum,
    unsigned long long* __restrict__ pub) {

  __shared__ float P_lds[NN];
  __shared__ float sig_lds[LSIG];
  __shared__ float red_lds[8][2];
  __shared__ float stage[8][16];   // own-rows output staging (flush every 16 steps)

  const int tid   = threadIdx.x;
  const int b     = blockIdx.x;
  const int w     = tid >> 6;      // wave 0..7
  const int lane  = tid & 63;
  const int p2    = w >> 1;        // row-pair 0..3
  const int h     = w & 1;         // i-range half
  const int row0  = b * 8 + p2 * 2;
  const int slot0 = tid * 4;
  const bool own  = ((tid >> 1) == b);   // threads 2b, 2b+1 own the block's 8 rows

  if (tid < LSIG) sig_lds[tid] = sig[tid];

  // wt{0,1}[4m+d] = W^T[row,i] = A[row][i]/(colsum[i]+eps), i = h*1024 + 256m + 4*lane + d
  // (consecutive lanes -> consecutive float4 of P: conflict-free ds_read_b128)
  float wt0[16], wt1[16];
  {
    const float* a0 = A + (size_t)row0 * NN;
    const float* a1 = a0 + NN;
#pragma unroll
    for (int m = 0; m < 4; ++m) {
      int ib = h * 1024 + m * 256 + lane * 4;
#pragma unroll
      for (int d = 0; d < 4; ++d) {
        float c = colsum[ib + d] + EPSC;
        wt0[4 * m + d] = a0[ib + d] / c;
        wt1[4 * m + d] = a1[ib + d] / c;
      }
    }
  }
  // rowsum(W)[j] = colsum[j]/(colsum[j]+eps) for this thread's 4 slots
  float rwv[4];
#pragma unroll
  for (int d = 0; d < 4; ++d) {
    float c = colsum[slot0 + d];
    rwv[d] = c / (c + EPSC);
  }
  float Pp[4] = {0.f, 0.f, 0.f, 0.f};   // momentum state for own slots (registers)
#pragma unroll
  for (int k = 0; k < 4; ++k) P_lds[slot0 + k] = 0.f;
  __syncthreads();

  for (int t = 0; t < TT; ++t) {
    const float s_t = sig_lds[t % (LSIG - 1)];

    // ---- poll tagged values for this step (parity t&1); tag>=t means ready.
    // t=0 satisfied by zero-init (tag 0, value 0).
    unsigned long long* ps = pub + (size_t)(t & 1) * NN + slot0;
    float val[4];
    {
      const unsigned int want = (unsigned int)t;
      for (;;) {
        unsigned long long x0 = __hip_atomic_load(ps + 0, __ATOMIC_RELAXED, __HIP_MEMORY_SCOPE_AGENT);
        unsigned long long x1 = __hip_atomic_load(ps + 1, __ATOMIC_RELAXED, __HIP_MEMORY_SCOPE_AGENT);
        unsigned long long x2 = __hip_atomic_load(ps + 2, __ATOMIC_RELAXED, __HIP_MEMORY_SCOPE_AGENT);
        unsigned long long x3 = __hip_atomic_load(ps + 3, __ATOMIC_RELAXED, __HIP_MEMORY_SCOPE_AGENT);
        if ((unsigned)(x0 >> 32) >= want && (unsigned)(x1 >> 32) >= want &&
            (unsigned)(x2 >> 32) >= want && (unsigned)(x3 >> 32) >= want) {
          val[0] = __uint_as_float((unsigned)x0);
          val[1] = __uint_as_float((unsigned)x1);
          val[2] = __uint_as_float((unsigned)x2);
          val[3] = __uint_as_float((unsigned)x3);
          break;
        }
        __builtin_amdgcn_s_sleep(1);
      }
    }

    // ---- S = Snext_prev + s_t ; P = fma(mom, P, S); expose P for matvec
    float Sl[4];
#pragma unroll
    for (int k = 0; k < 4; ++k) {
      float S = val[k] + s_t;
      Pp[k] = fmaf(MOMC, Pp[k], S);
      P_lds[slot0 + k] = Pp[k];
      Sl[k] = S;
    }
    // out staging: own rows, full 64B lines every 16 steps
    if (own) {
      const int r0 = (tid & 1) * 4;
#pragma unroll
      for (int k = 0; k < 4; ++k) stage[r0 + k][t & 15] = Sl[k];
      if ((t & 15) == 15) {
#pragma unroll
        for (int k = 0; k < 4; ++k) {
          float4* dst = (float4*)(out + (size_t)(slot0 + k) * TT + (t - 15));
          const float* sr = &stage[r0 + k][0];
          dst[0] = *(const float4*)(sr + 0);
          dst[1] = *(const float4*)(sr + 4);
          dst[2] = *(const float4*)(sr + 8);
          dst[3] = *(const float4*)(sr + 12);
        }
      }
    }
    __syncthreads();   // bar1: P_lds complete

    // ---- y[j] = sum_i W^T[j,i] * P[i] for this wave's 2 rows (half h)
    float y0 = 0.f, y1 = 0.f;
#pragma unroll
    for (int m = 0; m < 4; ++m) {
      const float4 q = *(const float4*)(P_lds + h * 1024 + m * 256 + lane * 4);
      y0 = fmaf(wt0[4 * m + 0], q.x, y0); y0 = fmaf(wt0[4 * m + 1], q.y, y0);
      y0 = fmaf(wt0[4 * m + 2], q.z, y0); y0 = fmaf(wt0[4 * m + 3], q.w, y0);
      y1 = fmaf(wt1[4 * m + 0], q.x, y1); y1 = fmaf(wt1[4 * m + 1], q.y, y1);
      y1 = fmaf(wt1[4 * m + 2], q.z, y1); y1 = fmaf(wt1[4 * m + 3], q.w, y1);
    }
#pragma unroll
    for (int m = 1; m < 64; m <<= 1) { y0 += __shfl_xor(y0, m); y1 += __shfl_xor(y1, m); }
    if (lane == 0) { red_lds[w][0] = y0; red_lds[w][1] = y1; }
    __syncthreads();   // bar2: red_lds complete
    // (red_lds reuse next iter is safe: its next write is after bar1-next, which
    //  the publishing threads must also reach)

    // ---- owners compute Snext for their 4 rows; publish (tag t+1, parity (t+1)&1)
    if (own) {
      const int r0 = (tid & 1) * 4;
      unsigned long long* pd = pub + (size_t)((t + 1) & 1) * NN + slot0;
      const unsigned long long tg = ((unsigned long long)(unsigned)(t + 1)) << 32;
#pragma unroll
      for (int d = 0; d < 4; ++d) {
        int jj = r0 + d;
        float y = red_lds[(jj >> 1) * 2][jj & 1] + red_lds[(jj >> 1) * 2 + 1][jj & 1];
        float sn = (Sl[d] + y) - Pp[d] * rwv[d];
        __hip_atomic_store(pd + d, tg | (unsigned long long)__float_as_uint(sn),
                           __ATOMIC_RELAXED, __HIP_MEMORY_SCOPE_AGENT);
      }
    }
  }
}

extern "C" void kernel_launch(void* const* d_in, const int* in_sizes, int n_in,
                              void* d_out, int out_size, void* d_ws, size_t ws_size,
                              hipStream_t stream) {
  const float* A   = (const float*)d_in[0];
  const float* sig = (const float*)d_in[1];
  float* out = (float*)d_out;
  char*  ws  = (char*)d_ws;

  unsigned long long* pub = (unsigned long long*)ws;
  float* colsum = (float*)(ws + 32768);

  sp_init<<<32, 256, 0, stream>>>((unsigned int*)ws);
  sp_colsum<<<NBLK, 256, 0, stream>>>(A, colsum);
  sp_persist<<<NBLK, NTHR, 0, stream>>>(A, sig, out, colsum, pub);
}

// Round 5
// 8875.874 us; speedup vs baseline: 2.5933x; 1.2676x over previous
//
#include <hip/hip_runtime.h>

#define NN   2048
#define TT   2048
#define LSIG 128
#define MOMC 0.999f
#define EPSC 1e-32f
#define NBLK 64      // persistent blocks; 32 rows each
#define NTHR 512     // 8 waves; each wave owns 4 rows
#define RPB  32

// ws layout: pub ull[2][2048] @ 0 (32 KB); colsum float[2048] @ 32768 (8 KB)
// pub word: (tag<<32) | float_bits ; tag t+1 = "Snext feeding step t+1", parity (t+1)&1
#define WS_WORDS ((32768 + 8192) / 4)

__global__ void sp_init(unsigned int* ws) {
  int i = blockIdx.x * blockDim.x + threadIdx.x;
  int stride = gridDim.x * blockDim.x;
  for (; i < WS_WORDS; i += stride) ws[i] = 0u;
}

__global__ void sp_colsum(const float* __restrict__ A, float* __restrict__ colsum) {
  int b = blockIdx.x;  // 256 blocks x 8 rows
  for (int c = threadIdx.x; c < NN; c += blockDim.x) {
    float s = 0.f;
#pragma unroll
    for (int r = 0; r < 8; ++r) s += A[(size_t)(b * 8 + r) * NN + c];
    atomicAdd(&colsum[c], s);
  }
}

__global__ __launch_bounds__(NTHR) void sp_persist(
    const float* __restrict__ A, const float* __restrict__ sig,
    float* __restrict__ out, const float* __restrict__ colsum,
    unsigned long long* __restrict__ pub) {

  __shared__ float P_lds[NN];
  __shared__ float S_lds[NN];
  __shared__ float sig_lds[LSIG];
  __shared__ float rw_lds[RPB];
  __shared__ float stage[RPB][16];   // own-row output staging, flushed every 16 steps

  const int tid   = threadIdx.x;
  const int b     = blockIdx.x;
  const int w     = tid >> 6;        // wave 0..7
  const int lane  = tid & 63;
  const int slot0 = tid * 4;         // this thread's 4 state slots (global rows)
  const int growb = b * RPB + w * 4; // this wave's 4 output rows
  const bool own  = ((tid >> 3) == b); // threads 8b..8b+7 hold the block's 32 out rows

  if (tid < LSIG) sig_lds[tid] = sig[tid];
  if (tid < RPB) { float c = colsum[b * RPB + tid]; rw_lds[tid] = c / (c + EPSC); }

  // wt[r][4m+d] = A[growb+r][m*256+lane*4+d] / (colsum[col]+eps)   (rows of W^T)
  float wt[4][32];
#pragma unroll
  for (int r = 0; r < 4; ++r) {
    const float* ar = A + (size_t)(growb + r) * NN;
#pragma unroll
    for (int m = 0; m < 8; ++m) {
      const int ib = m * 256 + lane * 4;
#pragma unroll
      for (int d = 0; d < 4; ++d)
        wt[r][4 * m + d] = ar[ib + d] / (colsum[ib + d] + EPSC);
    }
  }

  float Pp[4] = {0.f, 0.f, 0.f, 0.f};   // momentum state for own 4 slots
  __syncthreads();

  for (int t = 0; t < TT; ++t) {
    const float s_t = sig_lds[t % (LSIG - 1)];

    // ---- poll fused (tag|value) words for this step; cache ready slots
    float val[4];
    {
      unsigned long long* ps = pub + (size_t)(t & 1) * NN + slot0;
      const unsigned want = (unsigned)t;
      unsigned rdy = 0;
      int spins = 0;
      while (rdy != 0xFu) {
#pragma unroll
        for (int k = 0; k < 4; ++k) {
          if (!(rdy & (1u << k))) {
            unsigned long long x =
                __hip_atomic_load(ps + k, __ATOMIC_RELAXED, __HIP_MEMORY_SCOPE_AGENT);
            if ((unsigned)(x >> 32) >= want) {
              val[k] = __uint_as_float((unsigned)x);
              rdy |= (1u << k);
            }
          }
        }
        if (rdy != 0xFu && ++spins > 4) __builtin_amdgcn_s_sleep(2);
      }
    }

    // ---- S = prev + s_t ; P = fma(mom,P,S) ; expose to LDS; stage own outputs
    {
      float Sl[4];
#pragma unroll
      for (int k = 0; k < 4; ++k) {
        float S = val[k] + s_t;
        Pp[k] = fmaf(MOMC, Pp[k], S);
        P_lds[slot0 + k] = Pp[k];
        S_lds[slot0 + k] = S;
        Sl[k] = S;
      }
      if (own) {
        const int lr = 4 * (tid - 8 * b);   // local row base 0..28
#pragma unroll
        for (int k = 0; k < 4; ++k) stage[lr + k][t & 15] = Sl[k];
        if ((t & 15) == 15) {
#pragma unroll
          for (int k = 0; k < 4; ++k) {
            float4* dst = (float4*)(out + (size_t)(slot0 + k) * TT + (t - 15));
            const float* sr = &stage[lr + k][0];
            dst[0] = *(const float4*)(sr + 0);
            dst[1] = *(const float4*)(sr + 4);
            dst[2] = *(const float4*)(sr + 8);
            dst[3] = *(const float4*)(sr + 12);
          }
        }
      }
    }
    __syncthreads();   // bar1: P_lds/S_lds complete

    // ---- y[r] = sum_i W^T[growb+r, i] * P[i]  (full 2048 per wave, 32 cols/lane)
    float y[4] = {0.f, 0.f, 0.f, 0.f};
#pragma unroll
    for (int m = 0; m < 8; ++m) {
      const float4 q = *(const float4*)(P_lds + m * 256 + lane * 4);
#pragma unroll
      for (int r = 0; r < 4; ++r) {
        y[r] = fmaf(wt[r][4 * m + 0], q.x, y[r]);
        y[r] = fmaf(wt[r][4 * m + 1], q.y, y[r]);
        y[r] = fmaf(wt[r][4 * m + 2], q.z, y[r]);
        y[r] = fmaf(wt[r][4 * m + 3], q.w, y[r]);
      }
    }
#pragma unroll
    for (int msk = 1; msk < 64; msk <<= 1) {
#pragma unroll
      for (int r = 0; r < 4; ++r) y[r] += __shfl_xor(y[r], msk);
    }

    // ---- lane0 computes Snext for the wave's 4 rows (reads LDS BEFORE barrier)
    float sn[4];
    if (lane == 0) {
#pragma unroll
      for (int d = 0; d < 4; ++d) {
        const int gr = growb + d;
        sn[d] = (S_lds[gr] + y[d]) - P_lds[gr] * rw_lds[w * 4 + d];
      }
    }
    __syncthreads();   // bar2: all LDS reads done; next-iter writes now safe

    // ---- publish after barrier (no vmcnt drain on critical path)
    if (lane == 0) {
      unsigned long long* pd = pub + (size_t)((t + 1) & 1) * NN + growb;
      const unsigned long long tg = ((unsigned long long)(unsigned)(t + 1)) << 32;
#pragma unroll
      for (int d = 0; d < 4; ++d)
        __hip_atomic_store(pd + d, tg | (unsigned long long)__float_as_uint(sn[d]),
                           __ATOMIC_RELAXED, __HIP_MEMORY_SCOPE_AGENT);
    }
  }
}

extern "C" void kernel_launch(void* const* d_in, const int* in_sizes, int n_in,
                              void* d_out, int out_size, void* d_ws, size_t ws_size,
                              hipStream_t stream) {
  const float* A   = (const float*)d_in[0];
  const float* sig = (const float*)d_in[1];
  float* out = (float*)d_out;
  char*  ws  = (char*)d_ws;

  unsigned long long* pub = (unsigned long long*)ws;
  float* colsum = (float*)(ws + 32768);

  sp_init<<<32, 256, 0, stream>>>((unsigned int*)ws);
  sp_colsum<<<256, 256, 0, stream>>>(A, colsum);
  sp_persist<<<NBLK, NTHR, 0, stream>>>(A, sig, out, colsum, pub);
}